// Round 5
// baseline (130.878 us; speedup 1.0000x reference)
//
#include <hip/hip_runtime.h>
#include <cstdint>
#include <cstddef>

typedef unsigned short u16;
typedef __attribute__((ext_vector_type(8))) short short8;
typedef __attribute__((ext_vector_type(4))) float f32x4;

__device__ __forceinline__ u16 f2bf(float f){
  union { float f; unsigned u; } c; c.f = f;
  unsigned u = c.u;
  u += 0x7fffu + ((u >> 16) & 1u);   // RNE
  return (u16)(u >> 16);
}
__device__ __forceinline__ unsigned pk2(float a, float b){
  union { float f; unsigned u; } ca, cb; ca.f = a; cb.f = b;
  return ((ca.u + 0x8000u) >> 16) | ((cb.u + 0x8000u) & 0xFFFF0000u);
}

// xT2 layout: [b][row 0..65][col 0..65][128ci] bf16, interior at (h+1, w+1).
#define XB_STRIDE 557568   // 66*66*128
#define XR_STRIDE 8448     // 66*128

// ---------------------------------------------------------------------------
// Kernel 0: zero the 1-wide halo ring of xT2 (260 positions per b).
// ---------------------------------------------------------------------------
__global__ __launch_bounds__(256) void zero_halo(u16* __restrict__ xT2)
{
  const int b = blockIdx.x, tid = threadIdx.x;
  u16* xb = xT2 + (size_t)b * XB_STRIDE;
  for (int i = tid; i < 4160; i += 256){       // 260 pos * 16 granules
    const int p = i >> 4, oct = i & 15;
    int row, col;
    if (p < 66)      { row = 0;        col = p; }
    else if (p < 132){ row = 65;       col = p - 66; }
    else if (p < 196){ row = p - 131;  col = 0; }
    else             { row = p - 195;  col = 65; }
    *(uint4*)(xb + row * XR_STRIDE + (col << 7) + (oct << 3)) =
        make_uint4(0u, 0u, 0u, 0u);
  }
}

// ---------------------------------------------------------------------------
// Kernel 1: transpose x [b][128ci][4096] fp32 -> padded xT2 bf16 + SE pool
// partials. 1D grid 512, b = bid&15 (bid%8 == b%8 -> L2 homing).
// ---------------------------------------------------------------------------
__global__ __launch_bounds__(256) void xpose_pool(
    const float* __restrict__ x, u16* __restrict__ xT2, float* __restrict__ part)
{
  const int bid = blockIdx.x;
  const int b = bid & 15, chunk = bid >> 4;
  const int pos0 = chunk << 7;
  const int tid = threadIdx.x;
  __shared__ u16 tile[16384];        // 32 KB, swizzled [row][g'][8ci]
  __shared__ float psum[128 * 33];
  const float* xb = x + ((size_t)b << 19) + pos0;
  const int p4 = (tid & 31) << 2;
  const int swz = (tid & 31) & 7;

  #pragma unroll
  for (int i = 0; i < 2; ++i){
    const int gci = (tid >> 5) + (i << 3);
    const int ci8 = gci << 3;
    float4 L[8];
    #pragma unroll
    for (int j = 0; j < 8; ++j)
      L[j] = *(const float4*)(xb + ((size_t)(ci8 + j) << 12) + p4);
    #pragma unroll
    for (int j = 0; j < 8; ++j)
      psum[(ci8 + j) * 33 + (tid & 31)] = L[j].x + L[j].y + L[j].z + L[j].w;
    const int gs = gci ^ swz;
    const float* e = (const float*)L;
    #pragma unroll
    for (int p = 0; p < 4; ++p){
      const int row = p4 + p;
      uint4 V;
      V.x = pk2(e[0 * 4 + p], e[1 * 4 + p]);
      V.y = pk2(e[2 * 4 + p], e[3 * 4 + p]);
      V.z = pk2(e[4 * 4 + p], e[5 * 4 + p]);
      V.w = pk2(e[6 * 4 + p], e[7 * 4 + p]);
      *(uint4*)(tile + (row << 7) + (gs << 3)) = V;
    }
  }
  __syncthreads();

  if (tid < 128){
    float s = 0.f;
    #pragma unroll 8
    for (int j = 0; j < 32; ++j) s += psum[tid * 33 + j];
    part[((b << 5) + chunk) * 128 + tid] = s;
  }

  u16* xo = xT2 + (size_t)b * XB_STRIDE;
  const int g = tid & 15, rb = (tid >> 4) << 3;
  #pragma unroll
  for (int r = 0; r < 8; ++r){
    const int row = rb + r;
    const int gs = g ^ ((row >> 2) & 7);
    uint4 v = *(const uint4*)(tile + (row << 7) + (gs << 3));
    const int pos = pos0 + row;
    const int h = pos >> 6, w = pos & 63;
    *(uint4*)(xo + (h + 1) * XR_STRIDE + ((w + 1) << 7) + (g << 3)) = v;
  }
}

// ---------------------------------------------------------------------------
// Kernel 2: finish pooling, SE MLP, softmax(logits/30) -> attn[16][4]
// ---------------------------------------------------------------------------
__global__ void attn_fc(const float* __restrict__ part, const float* __restrict__ w1,
                        const float* __restrict__ w2, const float* __restrict__ b2,
                        float* __restrict__ attn)
{
  const int b = blockIdx.x, t = threadIdx.x;
  __shared__ float sp[128];
  __shared__ float sh[33];
  __shared__ float sl[4];
  const float* pb = part + (b << 12);
  float s = 0.f;
  for (int c = 0; c < 32; ++c) s += pb[(c << 7) + t];
  sp[t] = s * (1.f / 4096.f);
  __syncthreads();
  if (t < 33){
    float h = 0.f;
    for (int ci = 0; ci < 128; ++ci) h += sp[ci] * w1[t * 128 + ci];
    sh[t] = fmaxf(h, 0.f);
  }
  __syncthreads();
  if (t < 4){
    float l = b2[t];
    for (int j = 0; j < 33; ++j) l += sh[j] * w2[t * 33 + j];
    sl[t] = l * (1.f / 30.f);
  }
  __syncthreads();
  if (t == 0){
    float m = fmaxf(fmaxf(sl[0], sl[1]), fmaxf(sl[2], sl[3]));
    float e0 = __expf(sl[0] - m), e1 = __expf(sl[1] - m);
    float e2 = __expf(sl[2] - m), e3 = __expf(sl[3] - m);
    float inv = 1.f / (e0 + e1 + e2 + e3);
    attn[(b << 2) + 0] = e0 * inv; attn[(b << 2) + 1] = e1 * inv;
    attn[(b << 2) + 2] = e2 * inv; attn[(b << 2) + 3] = e3 * inv;
  }
}

// ---------------------------------------------------------------------------
// Kernel 3 (v5): combine, no-LDS, homed. grid 256 = g(16 co-groups of 8)*16+b
// (bid%8 == b%8 -> wcomb[b] dirty lines home to conv's XCD). 256 thr.
// Each block: one b, 8 co's; 36 outputs/thread, W gathered via L1/L2/L3.
// ---------------------------------------------------------------------------
__global__ __launch_bounds__(256) void combine(
    const float* __restrict__ W, const float* __restrict__ bias,
    const float* __restrict__ attn, u16* __restrict__ wcomb,
    float* __restrict__ bcomb)
{
  const int bid = blockIdx.x;
  const int b = bid & 15, g = bid >> 4;
  const int tid = threadIdx.x;
  const float a0 = attn[(b << 2) + 0], a1 = attn[(b << 2) + 1];
  const float a2 = attn[(b << 2) + 2], a3 = attn[(b << 2) + 3];
  if (tid < 8){
    const int co = (g << 3) + tid;
    bcomb[(b << 7) + co] = a0 * bias[co] + a1 * bias[128 + co]
                         + a2 * bias[256 + co] + a3 * bias[384 + co];
  }
  u16* wob = wcomb + (size_t)b * 147456;
  #pragma unroll
  for (int i = 0; i < 36; ++i){
    const int idx = tid + (i << 8);          // 0..9215
    const int ci = idx & 127;
    const int t2 = idx >> 7;                 // 0..71
    const int cl = t2 / 9, tap = t2 - cl * 9;
    const int co = (g << 3) + cl;
    const size_t woff = (size_t)co * 1152 + ci * 9 + tap;
    float s = a0 * W[woff]          + a1 * W[147456 + woff]
            + a2 * W[294912 + woff] + a3 * W[442368 + woff];
    wob[tap * 16384 + (co << 7) + ci] = f2bf(s);
  }
}

// ---------------------------------------------------------------------------
// Kernel 4 (v5): 9-tap implicit GEMM, bf16 MFMA 16x16x32. NO LDS, NO
// barriers: A and B frags straight from global (both perfectly coalesced,
// 16x64B lines per instr; L2-homed, kept resident by NT output stores).
// grid 2048 x 128 thr (2 waves: wc = co-half). Wave tile 64co x 32pos
// (acc[4][2]) -> 4096 waves total; launch_bounds(128,4) caps VGPR<=128 ->
// 4 waves/SIMD resident = 2x prior TLP.
// ---------------------------------------------------------------------------
__global__ __launch_bounds__(128, 4) void conv_mfma(
    const u16* __restrict__ xT2, const u16* __restrict__ wcomb,
    const float* __restrict__ bcomb, float* __restrict__ out)
{
  const int tid = threadIdx.x;
  const int lane = tid & 63, wc = tid >> 6;
  const int l15 = lane & 15, hi = lane >> 4;

  const int bid = blockIdx.x;
  const int xcd = bid & 7, j = bid >> 3;       // j 0..255
  const int b = ((j >> 7) << 3) | xcd;         // b%8 == xcd (L2 homing)
  const int rem = j & 127;
  const int h = rem >> 1;                      // output row 0..63
  const int wh = rem & 1;                      // pos half: cols wh*32..+32

  f32x4 acc[4][2] = {};

  const u16* A0 = wcomb + (size_t)b * 147456 + (wc << 13) + l15 * 128 + (hi << 3);
  const u16* B0 = xT2 + (size_t)b * XB_STRIDE + (wh << 5) * 128 + l15 * 128 + (hi << 3);

  #pragma unroll 3
  for (int tap = 0; tap < 9; ++tap){
    const int dh = tap / 3, dw = tap - 3 * dh;
    const u16* wt = A0 + tap * 16384;
    const u16* xr = B0 + (h + dh) * XR_STRIDE + (dw << 7);
    #pragma unroll
    for (int kc = 0; kc < 4; ++kc){
      const int ko = kc << 5;                  // koct*8 = (kc*4)*8
      short8 af[4], bfr[2];
      af[0] = *(const short8*)(wt + ko);
      af[1] = *(const short8*)(wt + 2048 + ko);
      af[2] = *(const short8*)(wt + 4096 + ko);
      af[3] = *(const short8*)(wt + 6144 + ko);
      bfr[0] = *(const short8*)(xr + ko);
      bfr[1] = *(const short8*)(xr + 2048 + ko);
      #pragma unroll
      for (int cf = 0; cf < 4; ++cf){
        acc[cf][0] = __builtin_amdgcn_mfma_f32_16x16x32_bf16(af[cf], bfr[0], acc[cf][0], 0, 0, 0);
        acc[cf][1] = __builtin_amdgcn_mfma_f32_16x16x32_bf16(af[cf], bfr[1], acc[cf][1], 0, 0, 0);
      }
    }
  }

  // ---- epilogue: C/D col=lane&15 (pos), row=(lane>>4)*4+reg (co). NT stores.
  float* ob = out + ((size_t)b << 19) + (h << 6) + (wh << 5) + l15;
  #pragma unroll
  for (int cf = 0; cf < 4; ++cf){
    const int co0 = (wc << 6) + (cf << 4) + (hi << 2);
    #pragma unroll
    for (int r = 0; r < 4; ++r){
      const float bc = bcomb[(b << 7) + co0 + r];
      float* op = ob + (size_t)(co0 + r) * 4096;
      __builtin_nontemporal_store(acc[cf][0][r] + bc, op);
      __builtin_nontemporal_store(acc[cf][1][r] + bc, op + 16);
    }
  }
}

// ---------------------------------------------------------------------------
extern "C" void kernel_launch(void* const* d_in, const int* in_sizes, int n_in,
                              void* d_out, int out_size, void* d_ws, size_t ws_size,
                              hipStream_t stream)
{
  const float* x    = (const float*)d_in[0];
  const float* W    = (const float*)d_in[1];
  const float* bias = (const float*)d_in[2];
  const float* w1   = (const float*)d_in[3];
  const float* w2   = (const float*)d_in[4];
  const float* b2   = (const float*)d_in[5];
  float* out = (float*)d_out;

  char* ws = (char*)d_ws;
  float* part  = (float*)(ws);               // 262144 B
  float* attn  = (float*)(ws + 262144);      // 256 B
  float* bcomb = (float*)(ws + 262400);      // 8192 B
  u16*   xT2   = (u16*)  (ws + 270592);      // 16*557568*2 = 17,842,176 B
  u16*   wcomb = (u16*)  (ws + 18112768);    // 4,718,592 B (end ~22.8 MB)

  zero_halo<<<16, 256, 0, stream>>>(xT2);
  xpose_pool<<<512, 256, 0, stream>>>(x, xT2, part);
  attn_fc<<<16, 128, 0, stream>>>(part, w1, w2, b2, attn);
  combine<<<256, 256, 0, stream>>>(W, bias, attn, wcomb, bcomb);
  conv_mfma<<<2048, 128, 0, stream>>>(xT2, wcomb, bcomb, out);
}

// Round 6
// 67.777 us; speedup vs baseline: 1.9310x; 1.9310x over previous
//
#include <hip/hip_runtime.h>
#include <cstdint>
#include <cstddef>

typedef unsigned short u16;
typedef __attribute__((ext_vector_type(8))) short short8;
typedef __attribute__((ext_vector_type(4))) float f32x4;

__device__ __forceinline__ u16 f2bf(float f){
  union { float f; unsigned u; } c; c.f = f;
  unsigned u = c.u;
  u += 0x7fffu + ((u >> 16) & 1u);   // RNE
  return (u16)(u >> 16);
}
__device__ __forceinline__ unsigned pk2(float a, float b){
  union { float f; unsigned u; } ca, cb; ca.f = a; cb.f = b;
  return ((ca.u + 0x8000u) >> 16) | ((cb.u + 0x8000u) & 0xFFFF0000u);
}

// xT2 layout: [b][row 0..65][col 0..65][128ci] bf16, interior at (h+1, w+1).
#define XB_STRIDE 557568   // 66*66*128 (u16 elements)
#define XR_STRIDE 8448     // 66*128

// direct-to-LDS 16B async copy (per-lane global src, wave-uniform LDS dst)
#define GLD_LDS(gsrc, ldst) \
  __builtin_amdgcn_global_load_lds((const __attribute__((address_space(1))) void*)(gsrc), \
                                   (__attribute__((address_space(3))) void*)(ldst), 16, 0, 0)

// ---------------------------------------------------------------------------
// Kernel 0: zero the 1-wide halo ring of xT2 (260 positions per b).
// ---------------------------------------------------------------------------
__global__ __launch_bounds__(256) void zero_halo(u16* __restrict__ xT2)
{
  const int b = blockIdx.x, tid = threadIdx.x;
  u16* xb = xT2 + (size_t)b * XB_STRIDE;
  for (int i = tid; i < 4160; i += 256){       // 260 pos * 16 granules
    const int p = i >> 4, oct = i & 15;
    int row, col;
    if (p < 66)      { row = 0;        col = p; }
    else if (p < 132){ row = 65;       col = p - 66; }
    else if (p < 196){ row = p - 131;  col = 0; }
    else             { row = p - 195;  col = 65; }
    *(uint4*)(xb + row * XR_STRIDE + (col << 7) + (oct << 3)) =
        make_uint4(0u, 0u, 0u, 0u);
  }
}

// ---------------------------------------------------------------------------
// Kernel 1: transpose x [b][128ci][4096] fp32 -> padded xT2 bf16 + SE pool
// partials. 1D grid 512, b = bid&15 (bid%8 == b%8 -> L2 homing).
// ---------------------------------------------------------------------------
__global__ __launch_bounds__(256) void xpose_pool(
    const float* __restrict__ x, u16* __restrict__ xT2, float* __restrict__ part)
{
  const int bid = blockIdx.x;
  const int b = bid & 15, chunk = bid >> 4;
  const int pos0 = chunk << 7;
  const int tid = threadIdx.x;
  __shared__ u16 tile[16384];        // 32 KB, swizzled [row][g'][8ci]
  __shared__ float psum[128 * 33];
  const float* xb = x + ((size_t)b << 19) + pos0;
  const int p4 = (tid & 31) << 2;
  const int swz = (tid & 31) & 7;

  #pragma unroll
  for (int i = 0; i < 2; ++i){
    const int gci = (tid >> 5) + (i << 3);
    const int ci8 = gci << 3;
    float4 L[8];
    #pragma unroll
    for (int j = 0; j < 8; ++j)
      L[j] = *(const float4*)(xb + ((size_t)(ci8 + j) << 12) + p4);
    #pragma unroll
    for (int j = 0; j < 8; ++j)
      psum[(ci8 + j) * 33 + (tid & 31)] = L[j].x + L[j].y + L[j].z + L[j].w;
    const int gs = gci ^ swz;
    const float* e = (const float*)L;
    #pragma unroll
    for (int p = 0; p < 4; ++p){
      const int row = p4 + p;
      uint4 V;
      V.x = pk2(e[0 * 4 + p], e[1 * 4 + p]);
      V.y = pk2(e[2 * 4 + p], e[3 * 4 + p]);
      V.z = pk2(e[4 * 4 + p], e[5 * 4 + p]);
      V.w = pk2(e[6 * 4 + p], e[7 * 4 + p]);
      *(uint4*)(tile + (row << 7) + (gs << 3)) = V;
    }
  }
  __syncthreads();

  if (tid < 128){
    float s = 0.f;
    #pragma unroll 8
    for (int j = 0; j < 32; ++j) s += psum[tid * 33 + j];
    part[((b << 5) + chunk) * 128 + tid] = s;
  }

  u16* xo = xT2 + (size_t)b * XB_STRIDE;
  const int g = tid & 15, rb = (tid >> 4) << 3;
  #pragma unroll
  for (int r = 0; r < 8; ++r){
    const int row = rb + r;
    const int gs = g ^ ((row >> 2) & 7);
    uint4 v = *(const uint4*)(tile + (row << 7) + (gs << 3));
    const int pos = pos0 + row;
    const int h = pos >> 6, w = pos & 63;
    *(uint4*)(xo + (h + 1) * XR_STRIDE + ((w + 1) << 7) + (g << 3)) = v;
  }
}

// ---------------------------------------------------------------------------
// Kernel 2: finish pooling, SE MLP, softmax(logits/30) -> attn[16][4]
// ---------------------------------------------------------------------------
__global__ void attn_fc(const float* __restrict__ part, const float* __restrict__ w1,
                        const float* __restrict__ w2, const float* __restrict__ b2,
                        float* __restrict__ attn)
{
  const int b = blockIdx.x, t = threadIdx.x;
  __shared__ float sp[128];
  __shared__ float sh[33];
  __shared__ float sl[4];
  const float* pb = part + (b << 12);
  float s = 0.f;
  for (int c = 0; c < 32; ++c) s += pb[(c << 7) + t];
  sp[t] = s * (1.f / 4096.f);
  __syncthreads();
  if (t < 33){
    float h = 0.f;
    for (int ci = 0; ci < 128; ++ci) h += sp[ci] * w1[t * 128 + ci];
    sh[t] = fmaxf(h, 0.f);
  }
  __syncthreads();
  if (t < 4){
    float l = b2[t];
    for (int j = 0; j < 33; ++j) l += sh[j] * w2[t * 33 + j];
    sl[t] = l * (1.f / 30.f);
  }
  __syncthreads();
  if (t == 0){
    float m = fmaxf(fmaxf(sl[0], sl[1]), fmaxf(sl[2], sl[3]));
    float e0 = __expf(sl[0] - m), e1 = __expf(sl[1] - m);
    float e2 = __expf(sl[2] - m), e3 = __expf(sl[3] - m);
    float inv = 1.f / (e0 + e1 + e2 + e3);
    attn[(b << 2) + 0] = e0 * inv; attn[(b << 2) + 1] = e1 * inv;
    attn[(b << 2) + 2] = e2 * inv; attn[(b << 2) + 3] = e3 * inv;
  }
}

// ---------------------------------------------------------------------------
// Kernel 3 (v6): combine -> PRE-SWIZZLED wcomb for linear LDS staging.
// wcomb u16 idx: (b*18 + tap*2 + c)*8192 + co*64 + ((g ^ (co&7))<<3) + e
//   where ci = c*64 + g*8 + e. bcomb[b][co] as before.
// grid 1024 = q(64 co-pairs)*16 + b  (bid%8 == b%8 -> homing). 256 thr.
// ---------------------------------------------------------------------------
__global__ __launch_bounds__(256) void combine(
    const float* __restrict__ W, const float* __restrict__ bias,
    const float* __restrict__ attn, u16* __restrict__ wcomb,
    float* __restrict__ bcomb)
{
  const int bid = blockIdx.x;
  const int b = bid & 15, q = bid >> 4;     // q: co-pair 0..63
  const int tid = threadIdx.x;
  const float a0 = attn[(b << 2) + 0], a1 = attn[(b << 2) + 1];
  const float a2 = attn[(b << 2) + 2], a3 = attn[(b << 2) + 3];
  if (tid < 2){
    const int co = (q << 1) + tid;
    bcomb[(b << 7) + co] = a0 * bias[co] + a1 * bias[128 + co]
                         + a2 * bias[256 + co] + a3 * bias[384 + co];
  }
  u16* wob = wcomb + (size_t)b * 147456;
  for (int gi = tid; gi < 288; gi += 256){  // 2co * 9tap * 2c * 8g granules
    const int co_l = gi / 144;
    const int r = gi - co_l * 144;
    const int tap = r >> 4;
    const int gg = r & 15;
    const int c = gg >> 3, g = gg & 7;
    const int co = (q << 1) + co_l;
    union { u16 h[8]; uint4 v; } pk;
    #pragma unroll
    for (int e = 0; e < 8; ++e){
      const int ci = (c << 6) + (g << 3) + e;
      const size_t woff = (size_t)(co << 7 | ci) * 9 + tap;
      float s = a0 * W[woff]          + a1 * W[147456 + woff]
              + a2 * W[294912 + woff] + a3 * W[442368 + woff];
      pk.h[e] = f2bf(s);
    }
    *(uint4*)(wob + (size_t)(tap * 2 + c) * 8192 + (co << 6) + ((g ^ (co & 7)) << 3)) = pk.v;
  }
}

// ---------------------------------------------------------------------------
// Kernel 4 (v6, m97-faithful): 9-tap implicit GEMM, bf16 MFMA 16x16x32.
// Block: 128co x (2 h-rows x 64 w), 4 waves (wave = 64co x 64pos, acc[4][4]).
// 18 K-steps (tap, ci-half): stage A 16KB (linear, pre-swizzled in mem) +
// B 16KB (per-lane swizzled src) via global_load_lds w16; 2 barriers/step.
// LDS 32KB -> 4 blocks/CU (launch_bounds(256,4)) = 16 waves/CU.
// ds_reads conflict-uniform via oct^(row&7) swizzle. grid 512, b homed.
// ---------------------------------------------------------------------------
__global__ __launch_bounds__(256, 4) void conv_mfma(
    const u16* __restrict__ xT2, const u16* __restrict__ wcomb,
    const float* __restrict__ bcomb, float* __restrict__ out)
{
  extern __shared__ char smem[];
  u16* s_a = (u16*)smem;             // [128co][8 oct-slots][8] = 16KB
  u16* s_b = (u16*)(smem + 16384);   // [128pos][8 oct-slots][8] = 16KB

  const int tid = threadIdx.x;
  const int lane = tid & 63, wid = tid >> 6;
  const int wr = wid & 1, wcv = wid >> 1;    // wr: h-row, wcv: co-half
  const int l15 = lane & 15, hi = lane >> 4;
  const int sw7 = l15 & 7;

  const int bid = blockIdx.x;
  const int b = bid & 15;                    // bid%8 == b%8 (L2 homing)
  const int h0 = (bid >> 4) << 1;            // 2 output rows

  f32x4 acc[4][4] = {};
  const u16* Abase = wcomb + (size_t)b * 147456;
  const u16* Xbase = xT2 + (size_t)b * XB_STRIDE;

  for (int step = 0; step < 18; ++step){
    const int tap = step >> 1, c = step & 1;
    const int dh = tap / 3, dw = tap - 3 * dh;

    __syncthreads();   // all waves done reading previous step's tiles

    // ---- stage A (linear 16KB; swizzle pre-baked in wcomb layout) ----
    {
      const u16* As = Abase + (size_t)step * 8192;
      #pragma unroll
      for (int it = 0; it < 4; ++it){
        const int gbase = it * 256 + wid * 64;
        GLD_LDS(As + ((gbase + lane) << 3), s_a + (gbase << 3));
      }
    }
    // ---- stage B (per-lane swizzled global src -> linear LDS) ----
    {
      #pragma unroll
      for (int it = 0; it < 4; ++it){
        const int gbase = it * 256 + wid * 64;
        const int G = gbase + lane;
        const int pos = G >> 3, gp = G & 7;
        const int pr = pos >> 6, w = pos & 63;
        const u16* src = Xbase + (h0 + pr + dh) * XR_STRIDE + ((w + dw) << 7)
                       + (c << 6) + ((gp ^ (pos & 7)) << 3);
        GLD_LDS(src, s_b + (gbase << 3));
      }
    }
    asm volatile("s_waitcnt vmcnt(0)" ::: "memory");
    __syncthreads();   // tiles ready

    // ---- compute: 2 k-substeps x (4 A-frags x 4 B-frags) MFMA ----
    #pragma unroll
    for (int ks = 0; ks < 2; ++ks){
      const int slot = ((ks << 2) + hi) ^ sw7;
      short8 af[4], bfr[4];
      #pragma unroll
      for (int a = 0; a < 4; ++a){
        const int co = (wcv << 6) + (a << 4) + l15;
        af[a] = *(const short8*)(s_a + (co << 6) + (slot << 3));
      }
      #pragma unroll
      for (int p = 0; p < 4; ++p){
        const int pos = (wr << 6) + (p << 4) + l15;
        bfr[p] = *(const short8*)(s_b + (pos << 6) + (slot << 3));
      }
      #pragma unroll
      for (int a = 0; a < 4; ++a)
        #pragma unroll
        for (int p = 0; p < 4; ++p)
          acc[a][p] = __builtin_amdgcn_mfma_f32_16x16x32_bf16(af[a], bfr[p], acc[a][p], 0, 0, 0);
    }
  }

  // ---- epilogue: C/D col=l15 (w), row=hi*4+r (co). NT stores. ----
  const int hrow = h0 + wr;
  float* ob = out + ((size_t)b << 19) + (hrow << 6) + l15;
  #pragma unroll
  for (int a = 0; a < 4; ++a){
    const int co0 = (wcv << 6) + (a << 4) + (hi << 2);
    #pragma unroll
    for (int r = 0; r < 4; ++r){
      const float bc = bcomb[(b << 7) + co0 + r];
      float* op = ob + (size_t)(co0 + r) * 4096;
      #pragma unroll
      for (int p = 0; p < 4; ++p)
        __builtin_nontemporal_store(acc[a][p][r] + bc, op + (p << 4));
    }
  }
}

// ---------------------------------------------------------------------------
extern "C" void kernel_launch(void* const* d_in, const int* in_sizes, int n_in,
                              void* d_out, int out_size, void* d_ws, size_t ws_size,
                              hipStream_t stream)
{
  const float* x    = (const float*)d_in[0];
  const float* W    = (const float*)d_in[1];
  const float* bias = (const float*)d_in[2];
  const float* w1   = (const float*)d_in[3];
  const float* w2   = (const float*)d_in[4];
  const float* b2   = (const float*)d_in[5];
  float* out = (float*)d_out;

  char* ws = (char*)d_ws;
  float* part  = (float*)(ws);               // 262144 B
  float* attn  = (float*)(ws + 262144);      // 256 B
  float* bcomb = (float*)(ws + 262400);      // 8192 B
  u16*   xT2   = (u16*)  (ws + 270592);      // 17,842,176 B
  u16*   wcomb = (u16*)  (ws + 18112768);    // 4,718,592 B (end ~22.8 MB)

  zero_halo<<<16, 256, 0, stream>>>(xT2);
  xpose_pool<<<512, 256, 0, stream>>>(x, xT2, part);
  attn_fc<<<16, 128, 0, stream>>>(part, w1, w2, b2, attn);
  combine<<<1024, 256, 0, stream>>>(W, bias, attn, wcomb, bcomb);
  conv_mfma<<<512, 256, 32768, stream>>>(xT2, wcomb, bcomb, out);
}

// Round 7
// 60.165 us; speedup vs baseline: 2.1753x; 1.1265x over previous
//
#include <hip/hip_runtime.h>
#include <cstdint>
#include <cstddef>

typedef unsigned short u16;
typedef __attribute__((ext_vector_type(8))) short short8;
typedef __attribute__((ext_vector_type(4))) float f32x4;

__device__ __forceinline__ u16 f2bf(float f){
  union { float f; unsigned u; } c; c.f = f;
  unsigned u = c.u;
  u += 0x7fffu + ((u >> 16) & 1u);   // RNE
  return (u16)(u >> 16);
}
__device__ __forceinline__ unsigned pk2(float a, float b){
  union { float f; unsigned u; } ca, cb; ca.f = a; cb.f = b;
  return ((ca.u + 0x8000u) >> 16) | ((cb.u + 0x8000u) & 0xFFFF0000u);
}

// xT2 layout: [b][row 0..65][col 0..65][128ci] bf16, interior at (h+1, w+1).
#define XB_STRIDE 557568   // 66*66*128 (u16 elements)
#define XR_STRIDE 8448     // 66*128

// direct-to-LDS 16B async copy (per-lane global src, wave-uniform LDS dst)
#define GLD_LDS(gsrc, ldst) \
  __builtin_amdgcn_global_load_lds((const __attribute__((address_space(1))) void*)(gsrc), \
                                   (__attribute__((address_space(3))) void*)(ldst), 16, 0, 0)

// ---------------------------------------------------------------------------
// Kernel 1: transpose x [b][128ci][4096] fp32 -> padded xT2 bf16 + SE pool
// partials. chunk==0 blocks also zero xT2[b]'s halo ring (fused zero_halo).
// 1D grid 512, b = bid&15 (bid%8 == b%8 -> L2 homing).
// ---------------------------------------------------------------------------
__global__ __launch_bounds__(256) void xpose_pool(
    const float* __restrict__ x, u16* __restrict__ xT2, float* __restrict__ part)
{
  const int bid = blockIdx.x;
  const int b = bid & 15, chunk = bid >> 4;
  const int pos0 = chunk << 7;
  const int tid = threadIdx.x;
  __shared__ u16 tile[16384];        // 32 KB, swizzled [row][g'][8ci]
  __shared__ float psum[128 * 33];
  const float* xb = x + ((size_t)b << 19) + pos0;
  const int p4 = (tid & 31) << 2;
  const int swz = (tid & 31) & 7;

  if (chunk == 0){                   // fused halo zeroing (disjoint from interior)
    u16* xh = xT2 + (size_t)b * XB_STRIDE;
    for (int i = tid; i < 4160; i += 256){     // 260 pos * 16 granules
      const int p = i >> 4, oct = i & 15;
      int row, col;
      if (p < 66)      { row = 0;        col = p; }
      else if (p < 132){ row = 65;       col = p - 66; }
      else if (p < 196){ row = p - 131;  col = 0; }
      else             { row = p - 195;  col = 65; }
      *(uint4*)(xh + row * XR_STRIDE + (col << 7) + (oct << 3)) =
          make_uint4(0u, 0u, 0u, 0u);
    }
  }

  #pragma unroll
  for (int i = 0; i < 2; ++i){
    const int gci = (tid >> 5) + (i << 3);
    const int ci8 = gci << 3;
    float4 L[8];
    #pragma unroll
    for (int j = 0; j < 8; ++j)
      L[j] = *(const float4*)(xb + ((size_t)(ci8 + j) << 12) + p4);
    #pragma unroll
    for (int j = 0; j < 8; ++j)
      psum[(ci8 + j) * 33 + (tid & 31)] = L[j].x + L[j].y + L[j].z + L[j].w;
    const int gs = gci ^ swz;
    const float* e = (const float*)L;
    #pragma unroll
    for (int p = 0; p < 4; ++p){
      const int row = p4 + p;
      uint4 V;
      V.x = pk2(e[0 * 4 + p], e[1 * 4 + p]);
      V.y = pk2(e[2 * 4 + p], e[3 * 4 + p]);
      V.z = pk2(e[4 * 4 + p], e[5 * 4 + p]);
      V.w = pk2(e[6 * 4 + p], e[7 * 4 + p]);
      *(uint4*)(tile + (row << 7) + (gs << 3)) = V;
    }
  }
  __syncthreads();

  if (tid < 128){
    float s = 0.f;
    #pragma unroll 8
    for (int j = 0; j < 32; ++j) s += psum[tid * 33 + j];
    part[((b << 5) + chunk) * 128 + tid] = s;
  }

  u16* xo = xT2 + (size_t)b * XB_STRIDE;
  const int g = tid & 15, rb = (tid >> 4) << 3;
  #pragma unroll
  for (int r = 0; r < 8; ++r){
    const int row = rb + r;
    const int gs = g ^ ((row >> 2) & 7);
    uint4 v = *(const uint4*)(tile + (row << 7) + (gs << 3));
    const int pos = pos0 + row;
    const int h = pos >> 6, w = pos & 63;
    *(uint4*)(xo + (h + 1) * XR_STRIDE + ((w + 1) << 7) + (g << 3)) = v;
  }
}

// ---------------------------------------------------------------------------
// Kernel 2: finish pooling, SE MLP, softmax(logits/30) -> attn[16][4]
// ---------------------------------------------------------------------------
__global__ void attn_fc(const float* __restrict__ part, const float* __restrict__ w1,
                        const float* __restrict__ w2, const float* __restrict__ b2,
                        float* __restrict__ attn)
{
  const int b = blockIdx.x, t = threadIdx.x;
  __shared__ float sp[128];
  __shared__ float sh[33];
  __shared__ float sl[4];
  const float* pb = part + (b << 12);
  float s = 0.f;
  for (int c = 0; c < 32; ++c) s += pb[(c << 7) + t];
  sp[t] = s * (1.f / 4096.f);
  __syncthreads();
  if (t < 33){
    float h = 0.f;
    for (int ci = 0; ci < 128; ++ci) h += sp[ci] * w1[t * 128 + ci];
    sh[t] = fmaxf(h, 0.f);
  }
  __syncthreads();
  if (t < 4){
    float l = b2[t];
    for (int j = 0; j < 33; ++j) l += sh[j] * w2[t * 33 + j];
    sl[t] = l * (1.f / 30.f);
  }
  __syncthreads();
  if (t == 0){
    float m = fmaxf(fmaxf(sl[0], sl[1]), fmaxf(sl[2], sl[3]));
    float e0 = __expf(sl[0] - m), e1 = __expf(sl[1] - m);
    float e2 = __expf(sl[2] - m), e3 = __expf(sl[3] - m);
    float inv = 1.f / (e0 + e1 + e2 + e3);
    attn[(b << 2) + 0] = e0 * inv; attn[(b << 2) + 1] = e1 * inv;
    attn[(b << 2) + 2] = e2 * inv; attn[(b << 2) + 3] = e3 * inv;
  }
}

// ---------------------------------------------------------------------------
// Kernel 3: combine -> PRE-SWIZZLED wcomb for linear LDS staging.
// wcomb u16 idx: (b*18 + tap*2 + c)*8192 + co*64 + ((g ^ (co&7))<<3) + e
//   where ci = c*64 + g*8 + e. bcomb[b][co] as before.
// grid 1024 = q(64 co-pairs)*16 + b  (bid%8 == b%8 -> homing). 256 thr.
// ---------------------------------------------------------------------------
__global__ __launch_bounds__(256) void combine(
    const float* __restrict__ W, const float* __restrict__ bias,
    const float* __restrict__ attn, u16* __restrict__ wcomb,
    float* __restrict__ bcomb)
{
  const int bid = blockIdx.x;
  const int b = bid & 15, q = bid >> 4;     // q: co-pair 0..63
  const int tid = threadIdx.x;
  const float a0 = attn[(b << 2) + 0], a1 = attn[(b << 2) + 1];
  const float a2 = attn[(b << 2) + 2], a3 = attn[(b << 2) + 3];
  if (tid < 2){
    const int co = (q << 1) + tid;
    bcomb[(b << 7) + co] = a0 * bias[co] + a1 * bias[128 + co]
                         + a2 * bias[256 + co] + a3 * bias[384 + co];
  }
  u16* wob = wcomb + (size_t)b * 147456;
  for (int gi = tid; gi < 288; gi += 256){  // 2co * 9tap * 2c * 8g granules
    const int co_l = gi / 144;
    const int r = gi - co_l * 144;
    const int tap = r >> 4;
    const int gg = r & 15;
    const int c = gg >> 3, g = gg & 7;
    const int co = (q << 1) + co_l;
    union { u16 h[8]; uint4 v; } pk;
    #pragma unroll
    for (int e = 0; e < 8; ++e){
      const int ci = (c << 6) + (g << 3) + e;
      const size_t woff = (size_t)(co << 7 | ci) * 9 + tap;
      float s = a0 * W[woff]          + a1 * W[147456 + woff]
              + a2 * W[294912 + woff] + a3 * W[442368 + woff];
      pk.h[e] = f2bf(s);
    }
    *(uint4*)(wob + (size_t)(tap * 2 + c) * 8192 + (co << 6) + ((g ^ (co & 7)) << 3)) = pk.v;
  }
}

// ---------------------------------------------------------------------------
// Kernel 4 (v7): v6 + T3 2-phase double-buffer. Per step: issue stage(t+1)
// into buf^1 FIRST (loads in flight), compute(t) on buf, vmcnt(0) (already
// ~drained), ONE barrier. LDS 2 x (16KB A + 16KB B) = 64KB -> 2 blocks/CU.
// Addressing identical to v6 (verified). grid 512 x 256 thr, b homed b%8.
// ---------------------------------------------------------------------------
__global__ __launch_bounds__(256, 2) void conv_mfma(
    const u16* __restrict__ xT2, const u16* __restrict__ wcomb,
    const float* __restrict__ bcomb, float* __restrict__ out)
{
  extern __shared__ char smem[];

  const int tid = threadIdx.x;
  const int lane = tid & 63, wid = tid >> 6;
  const int wr = wid & 1, wcv = wid >> 1;    // wr: h-row, wcv: co-half
  const int l15 = lane & 15, hi = lane >> 4;
  const int sw7 = l15 & 7;

  const int bid = blockIdx.x;
  const int b = bid & 15;                    // bid%8 == b%8 (L2 homing)
  const int h0 = (bid >> 4) << 1;            // 2 output rows

  const u16* Abase = wcomb + (size_t)b * 147456;
  const u16* Xbase = xT2 + (size_t)b * XB_STRIDE;

#define STAGE_STEP(S, BUF) { \
    const int _tap = (S) >> 1, _c = (S) & 1; \
    const int _dh = _tap / 3, _dw = _tap - 3 * _dh; \
    u16* _sa = (u16*)(smem + (BUF) * 32768); \
    u16* _sb = (u16*)(smem + (BUF) * 32768 + 16384); \
    const u16* _As = Abase + (size_t)(S) * 8192; \
    _Pragma("unroll") \
    for (int _it = 0; _it < 4; ++_it){ \
      const int _gb = _it * 256 + wid * 64; \
      GLD_LDS(_As + ((_gb + lane) << 3), _sa + (_gb << 3)); \
    } \
    _Pragma("unroll") \
    for (int _it = 0; _it < 4; ++_it){ \
      const int _gb = _it * 256 + wid * 64; \
      const int _G = _gb + lane; \
      const int _pos = _G >> 3, _gp = _G & 7; \
      const int _pr = _pos >> 6, _w = _pos & 63; \
      const u16* _src = Xbase + (h0 + _pr + _dh) * XR_STRIDE + ((_w + _dw) << 7) \
                      + (_c << 6) + ((_gp ^ (_pos & 7)) << 3); \
      GLD_LDS(_src, _sb + (_gb << 3)); \
    } }

#define COMPUTE_STEP(BUF) { \
    const u16* _sa = (const u16*)(smem + (BUF) * 32768); \
    const u16* _sb = (const u16*)(smem + (BUF) * 32768 + 16384); \
    _Pragma("unroll") \
    for (int _ks = 0; _ks < 2; ++_ks){ \
      const int _slot = ((_ks << 2) + hi) ^ sw7; \
      short8 _af[4], _bf[4]; \
      _Pragma("unroll") \
      for (int _a = 0; _a < 4; ++_a){ \
        const int _co = (wcv << 6) + (_a << 4) + l15; \
        _af[_a] = *(const short8*)(_sa + (_co << 6) + (_slot << 3)); \
      } \
      _Pragma("unroll") \
      for (int _p = 0; _p < 4; ++_p){ \
        const int _ps = (wr << 6) + (_p << 4) + l15; \
        _bf[_p] = *(const short8*)(_sb + (_ps << 6) + (_slot << 3)); \
      } \
      _Pragma("unroll") \
      for (int _a = 0; _a < 4; ++_a) \
        _Pragma("unroll") \
        for (int _p = 0; _p < 4; ++_p) \
          acc[_a][_p] = __builtin_amdgcn_mfma_f32_16x16x32_bf16(_af[_a], _bf[_p], acc[_a][_p], 0, 0, 0); \
    } }

  f32x4 acc[4][4] = {};

  STAGE_STEP(0, 0);
  asm volatile("s_waitcnt vmcnt(0)" ::: "memory");
  __syncthreads();

  #pragma unroll 2
  for (int step = 0; step < 18; ++step){
    const int cur = step & 1;
    if (step < 17) STAGE_STEP(step + 1, cur ^ 1);   // prefetch: in flight under MFMA
    COMPUTE_STEP(cur);
    asm volatile("s_waitcnt vmcnt(0)" ::: "memory"); // near-drained by now
    __syncthreads();                                 // one barrier per step
  }

#undef COMPUTE_STEP
#undef STAGE_STEP

  // ---- epilogue: C/D col=l15 (w), row=hi*4+r (co). NT stores. ----
  const int hrow = h0 + wr;
  float* ob = out + ((size_t)b << 19) + (hrow << 6) + l15;
  #pragma unroll
  for (int a = 0; a < 4; ++a){
    const int co0 = (wcv << 6) + (a << 4) + (hi << 2);
    #pragma unroll
    for (int r = 0; r < 4; ++r){
      const float bc = bcomb[(b << 7) + co0 + r];
      float* op = ob + (size_t)(co0 + r) * 4096;
      #pragma unroll
      for (int p = 0; p < 4; ++p)
        __builtin_nontemporal_store(acc[a][p][r] + bc, op + (p << 4));
    }
  }
}

// ---------------------------------------------------------------------------
extern "C" void kernel_launch(void* const* d_in, const int* in_sizes, int n_in,
                              void* d_out, int out_size, void* d_ws, size_t ws_size,
                              hipStream_t stream)
{
  const float* x    = (const float*)d_in[0];
  const float* W    = (const float*)d_in[1];
  const float* bias = (const float*)d_in[2];
  const float* w1   = (const float*)d_in[3];
  const float* w2   = (const float*)d_in[4];
  const float* b2   = (const float*)d_in[5];
  float* out = (float*)d_out;

  char* ws = (char*)d_ws;
  float* part  = (float*)(ws);               // 262144 B
  float* attn  = (float*)(ws + 262144);      // 256 B
  float* bcomb = (float*)(ws + 262400);      // 8192 B
  u16*   xT2   = (u16*)  (ws + 270592);      // 17,842,176 B
  u16*   wcomb = (u16*)  (ws + 18112768);    // 4,718,592 B (end ~22.8 MB)

  xpose_pool<<<512, 256, 0, stream>>>(x, xT2, part);
  attn_fc<<<16, 128, 0, stream>>>(part, w1, w2, b2, attn);
  combine<<<1024, 256, 0, stream>>>(W, bias, attn, wcomb, bcomb);

  (void)hipFuncSetAttribute(reinterpret_cast<const void*>(conv_mfma),
                            hipFuncAttributeMaxDynamicSharedMemorySize, 65536);
  conv_mfma<<<512, 256, 65536, stream>>>(xT2, wcomb, bcomb, out);
}

// Round 8
// 56.372 us; speedup vs baseline: 2.3217x; 1.0673x over previous
//
#include <hip/hip_runtime.h>
#include <cstdint>
#include <cstddef>

typedef unsigned short u16;
typedef __attribute__((ext_vector_type(8))) short short8;
typedef __attribute__((ext_vector_type(4))) float f32x4;

__device__ __forceinline__ u16 f2bf(float f){
  union { float f; unsigned u; } c; c.f = f;
  unsigned u = c.u;
  u += 0x7fffu + ((u >> 16) & 1u);   // RNE
  return (u16)(u >> 16);
}
__device__ __forceinline__ unsigned pk2(float a, float b){
  union { float f; unsigned u; } ca, cb; ca.f = a; cb.f = b;
  return ((ca.u + 0x8000u) >> 16) | ((cb.u + 0x8000u) & 0xFFFF0000u);
}

// xT2 layout: [b][row 0..65][col 0..65][128ci] bf16, interior at (h+1, w+1).
#define XB_STRIDE 557568   // 66*66*128 (u16 elements)
#define XR_STRIDE 8448     // 66*128

// direct-to-LDS 16B async copy (per-lane global src, wave-uniform LDS dst)
#define GLD_LDS(gsrc, ldst) \
  __builtin_amdgcn_global_load_lds((const __attribute__((address_space(1))) void*)(gsrc), \
                                   (__attribute__((address_space(3))) void*)(ldst), 16, 0, 0)

// ---------------------------------------------------------------------------
// Kernel 1: transpose x [b][128ci][4096] fp32 -> padded xT2 bf16 + SE pool
// partials. chunk==0 blocks also zero xT2[b]'s halo ring.
// 1D grid 512, b = bid&15 (bid%8 == b%8 -> L2 homing).
// ---------------------------------------------------------------------------
__global__ __launch_bounds__(256) void xpose_pool(
    const float* __restrict__ x, u16* __restrict__ xT2, float* __restrict__ part)
{
  const int bid = blockIdx.x;
  const int b = bid & 15, chunk = bid >> 4;
  const int pos0 = chunk << 7;
  const int tid = threadIdx.x;
  __shared__ u16 tile[16384];        // 32 KB, swizzled [row][g'][8ci]
  __shared__ float psum[128 * 33];
  const float* xb = x + ((size_t)b << 19) + pos0;
  const int p4 = (tid & 31) << 2;
  const int swz = (tid & 31) & 7;

  if (chunk == 0){                   // fused halo zeroing (disjoint from interior)
    u16* xh = xT2 + (size_t)b * XB_STRIDE;
    for (int i = tid; i < 4160; i += 256){     // 260 pos * 16 granules
      const int p = i >> 4, oct = i & 15;
      int row, col;
      if (p < 66)      { row = 0;        col = p; }
      else if (p < 132){ row = 65;       col = p - 66; }
      else if (p < 196){ row = p - 131;  col = 0; }
      else             { row = p - 195;  col = 65; }
      *(uint4*)(xh + row * XR_STRIDE + (col << 7) + (oct << 3)) =
          make_uint4(0u, 0u, 0u, 0u);
    }
  }

  #pragma unroll
  for (int i = 0; i < 2; ++i){
    const int gci = (tid >> 5) + (i << 3);
    const int ci8 = gci << 3;
    float4 L[8];
    #pragma unroll
    for (int j = 0; j < 8; ++j)
      L[j] = *(const float4*)(xb + ((size_t)(ci8 + j) << 12) + p4);
    #pragma unroll
    for (int j = 0; j < 8; ++j)
      psum[(ci8 + j) * 33 + (tid & 31)] = L[j].x + L[j].y + L[j].z + L[j].w;
    const int gs = gci ^ swz;
    const float* e = (const float*)L;
    #pragma unroll
    for (int p = 0; p < 4; ++p){
      const int row = p4 + p;
      uint4 V;
      V.x = pk2(e[0 * 4 + p], e[1 * 4 + p]);
      V.y = pk2(e[2 * 4 + p], e[3 * 4 + p]);
      V.z = pk2(e[4 * 4 + p], e[5 * 4 + p]);
      V.w = pk2(e[6 * 4 + p], e[7 * 4 + p]);
      *(uint4*)(tile + (row << 7) + (gs << 3)) = V;
    }
  }
  __syncthreads();

  if (tid < 128){
    float s = 0.f;
    #pragma unroll 8
    for (int j = 0; j < 32; ++j) s += psum[tid * 33 + j];
    part[((b << 5) + chunk) * 128 + tid] = s;
  }

  u16* xo = xT2 + (size_t)b * XB_STRIDE;
  const int g = tid & 15, rb = (tid >> 4) << 3;
  #pragma unroll
  for (int r = 0; r < 8; ++r){
    const int row = rb + r;
    const int gs = g ^ ((row >> 2) & 7);
    uint4 v = *(const uint4*)(tile + (row << 7) + (gs << 3));
    const int pos = pos0 + row;
    const int h = pos >> 6, w = pos & 63;
    *(uint4*)(xo + (h + 1) * XR_STRIDE + ((w + 1) << 7) + (g << 3)) = v;
  }
}

// ---------------------------------------------------------------------------
// Kernel 2: finish pooling, SE MLP, softmax(logits/30) -> attn[16][4]
// ---------------------------------------------------------------------------
__global__ void attn_fc(const float* __restrict__ part, const float* __restrict__ w1,
                        const float* __restrict__ w2, const float* __restrict__ b2,
                        float* __restrict__ attn)
{
  const int b = blockIdx.x, t = threadIdx.x;
  __shared__ float sp[128];
  __shared__ float sh[33];
  __shared__ float sl[4];
  const float* pb = part + (b << 12);
  float s = 0.f;
  for (int c = 0; c < 32; ++c) s += pb[(c << 7) + t];
  sp[t] = s * (1.f / 4096.f);
  __syncthreads();
  if (t < 33){
    float h = 0.f;
    for (int ci = 0; ci < 128; ++ci) h += sp[ci] * w1[t * 128 + ci];
    sh[t] = fmaxf(h, 0.f);
  }
  __syncthreads();
  if (t < 4){
    float l = b2[t];
    for (int j = 0; j < 33; ++j) l += sh[j] * w2[t * 33 + j];
    sl[t] = l * (1.f / 30.f);
  }
  __syncthreads();
  if (t == 0){
    float m = fmaxf(fmaxf(sl[0], sl[1]), fmaxf(sl[2], sl[3]));
    float e0 = __expf(sl[0] - m), e1 = __expf(sl[1] - m);
    float e2 = __expf(sl[2] - m), e3 = __expf(sl[3] - m);
    float inv = 1.f / (e0 + e1 + e2 + e3);
    attn[(b << 2) + 0] = e0 * inv; attn[(b << 2) + 1] = e1 * inv;
    attn[(b << 2) + 2] = e2 * inv; attn[(b << 2) + 3] = e3 * inv;
  }
}

// ---------------------------------------------------------------------------
// Kernel 3: combine -> PRE-SWIZZLED wcomb for linear LDS staging.
// wcomb u16 idx: (b*18 + tap*2 + c)*8192 + co*64 + ((g ^ (co&7))<<3) + e
//   where ci = c*64 + g*8 + e. bcomb[b][co] as before.
// grid 1024 = q(64 co-pairs)*16 + b  (bid%8 == b%8 -> homing). 256 thr.
// ---------------------------------------------------------------------------
__global__ __launch_bounds__(256) void combine(
    const float* __restrict__ W, const float* __restrict__ bias,
    const float* __restrict__ attn, u16* __restrict__ wcomb,
    float* __restrict__ bcomb)
{
  const int bid = blockIdx.x;
  const int b = bid & 15, q = bid >> 4;     // q: co-pair 0..63
  const int tid = threadIdx.x;
  const float a0 = attn[(b << 2) + 0], a1 = attn[(b << 2) + 1];
  const float a2 = attn[(b << 2) + 2], a3 = attn[(b << 2) + 3];
  if (tid < 2){
    const int co = (q << 1) + tid;
    bcomb[(b << 7) + co] = a0 * bias[co] + a1 * bias[128 + co]
                         + a2 * bias[256 + co] + a3 * bias[384 + co];
  }
  u16* wob = wcomb + (size_t)b * 147456;
  for (int gi = tid; gi < 288; gi += 256){  // 2co * 9tap * 2c * 8g granules
    const int co_l = gi / 144;
    const int r = gi - co_l * 144;
    const int tap = r >> 4;
    const int gg = r & 15;
    const int c = gg >> 3, g = gg & 7;
    const int co = (q << 1) + co_l;
    union { u16 h[8]; uint4 v; } pk;
    #pragma unroll
    for (int e = 0; e < 8; ++e){
      const int ci = (c << 6) + (g << 3) + e;
      const size_t woff = (size_t)(co << 7 | ci) * 9 + tap;
      float s = a0 * W[woff]          + a1 * W[147456 + woff]
              + a2 * W[294912 + woff] + a3 * W[442368 + woff];
      pk.h[e] = f2bf(s);
    }
    *(uint4*)(wob + (size_t)(tap * 2 + c) * 8192 + (co << 6) + ((g ^ (co & 7)) << 3)) = pk.v;
  }
}

// ---------------------------------------------------------------------------
// Kernel 4 (v8): x-tile staged ONCE per ci-half (stable B buffer); only the
// 16KB weight slab streams per step (double-buffered, T3 2-phase). Staging
// traffic = unique-data minimum (356KB/block). LDS: x 33792B + w 32768B =
// 66560B -> 2 blocks/CU. grid 512 x 256 thr (4 waves), b homed to XCD b%8.
// Addressing/swizzles identical to r6/r7-verified kernels.
// ---------------------------------------------------------------------------
__global__ __launch_bounds__(256, 2) void conv_mfma(
    const u16* __restrict__ xT2, const u16* __restrict__ wcomb,
    const float* __restrict__ bcomb, float* __restrict__ out)
{
  extern __shared__ char smem[];
  u16* s_x = (u16*)smem;               // [4row][66col][8oct][8ci] = 33792B
  u16* s_w = (u16*)(smem + 33792);     // 2 x 8192 u16 (16KB slabs)

  const int tid = threadIdx.x;
  const int lane = tid & 63, wid = tid >> 6;
  const int wr = wid & 1, wcv = wid >> 1;    // wr: h-row, wcv: co-half
  const int l15 = lane & 15, hi = lane >> 4;
  const int sw7 = l15 & 7;

  const int bid = blockIdx.x;
  const int b = bid & 15;                    // bid%8 == b%8 (L2 homing)
  const int h0 = (bid >> 4) << 1;            // 2 output rows

  const u16* Abase = wcomb + (size_t)b * 147456;
  const u16* Xbase = xT2 + (size_t)b * XB_STRIDE;

  // stage x ci-half C into s_x: 2112 granules; LDS slot oct holds global
  // koct = oct^(col&7)  (read undoes it) — pre-swizzled global src.
#define STAGE_X(C) { \
    _Pragma("unroll") \
    for (int _it = 0; _it < 9; ++_it){ \
      const int _G = _it * 256 + tid; \
      if (_it < 8 || _G < 2112){ \
        const int _oct = _G & 7, _t = _G >> 3; \
        const int _col = _t % 66, _row = _t / 66; \
        const u16* _src = Xbase + (h0 + _row) * XR_STRIDE + (_col << 7) \
                        + ((C) << 6) + ((_oct ^ (_col & 7)) << 3); \
        GLD_LDS(_src, s_x + (_G << 3)); \
      } \
    } }

#define STAGE_W(SLAB, BUF) { \
    const u16* _As = Abase + (size_t)(SLAB) * 8192; \
    u16* _sw = s_w + (BUF) * 8192; \
    _Pragma("unroll") \
    for (int _it = 0; _it < 4; ++_it){ \
      const int _G = _it * 256 + tid; \
      GLD_LDS(_As + (_G << 3), _sw + (_G << 3)); \
    } }

  // compute step s (c = s>=9, tap = s%9) from w buf BUF; B from stable s_x.
#define COMPUTE(S, BUF) { \
    const int _tap = (S) < 9 ? (S) : (S) - 9; \
    const int _dh = _tap / 3, _dw = _tap - 3 * _dh; \
    const int _b7 = (l15 + _dw) & 7; \
    const u16* _sw = s_w + (BUF) * 8192; \
    _Pragma("unroll") \
    for (int _ks = 0; _ks < 2; ++_ks){ \
      const int _k4 = (_ks << 2) + hi; \
      short8 _af[4], _bf[4]; \
      _Pragma("unroll") \
      for (int _a = 0; _a < 4; ++_a){ \
        const int _co = (wcv << 6) + (_a << 4) + l15; \
        _af[_a] = *(const short8*)(_sw + (_co << 6) + ((_k4 ^ sw7) << 3)); \
      } \
      _Pragma("unroll") \
      for (int _p = 0; _p < 4; ++_p){ \
        const int _col = l15 + _dw + (_p << 4); \
        _bf[_p] = *(const short8*)(s_x + ((((wr + _dh) * 66 + _col) << 3) \
                                          + (_k4 ^ _b7)) * 8); \
      } \
      _Pragma("unroll") \
      for (int _a = 0; _a < 4; ++_a) \
        _Pragma("unroll") \
        for (int _p = 0; _p < 4; ++_p) \
          acc[_a][_p] = __builtin_amdgcn_mfma_f32_16x16x32_bf16(_af[_a], _bf[_p], acc[_a][_p], 0, 0, 0); \
    } }

#define VM0_BAR { asm volatile("s_waitcnt vmcnt(0)" ::: "memory"); __syncthreads(); }

  f32x4 acc[4][4] = {};

  // slab(s) = (s<9) ? 2s : 2(s-9)+1
  STAGE_X(0);
  STAGE_W(0, 0);
  VM0_BAR;

  for (int s = 0; s < 8; ++s){                 // c=0, taps 0..7
    STAGE_W(2 * (s + 1), (s & 1) ^ 1);
    COMPUTE(s, s & 1);
    VM0_BAR;
  }
  // s = 8 (c=0 tap 8): prefetch slab(9)=1 into buf1, then restage x for c=1
  STAGE_W(1, 1);
  COMPUTE(8, 0);
  VM0_BAR;                                     // all waves done reading s_x(c=0)
  STAGE_X(1);
  VM0_BAR;
  for (int s = 9; s < 17; ++s){                // c=1, taps 0..7
    STAGE_W(2 * (s + 1 - 9) + 1, (s & 1) ^ 1);
    COMPUTE(s, s & 1);
    VM0_BAR;
  }
  COMPUTE(17, 1);                              // c=1 tap 8

#undef VM0_BAR
#undef COMPUTE
#undef STAGE_W
#undef STAGE_X

  // ---- epilogue: C/D col=l15 (w), row=hi*4+r (co). NT stores. ----
  const int hrow = h0 + wr;
  float* ob = out + ((size_t)b << 19) + (hrow << 6) + l15;
  #pragma unroll
  for (int a = 0; a < 4; ++a){
    const int co0 = (wcv << 6) + (a << 4) + (hi << 2);
    #pragma unroll
    for (int r = 0; r < 4; ++r){
      const float bc = bcomb[(b << 7) + co0 + r];
      float* op = ob + (size_t)(co0 + r) * 4096;
      #pragma unroll
      for (int p = 0; p < 4; ++p)
        __builtin_nontemporal_store(acc[a][p][r] + bc, op + (p << 4));
    }
  }
}

// ---------------------------------------------------------------------------
extern "C" void kernel_launch(void* const* d_in, const int* in_sizes, int n_in,
                              void* d_out, int out_size, void* d_ws, size_t ws_size,
                              hipStream_t stream)
{
  const float* x    = (const float*)d_in[0];
  const float* W    = (const float*)d_in[1];
  const float* bias = (const float*)d_in[2];
  const float* w1   = (const float*)d_in[3];
  const float* w2   = (const float*)d_in[4];
  const float* b2   = (const float*)d_in[5];
  float* out = (float*)d_out;

  char* ws = (char*)d_ws;
  float* part  = (float*)(ws);               // 262144 B
  float* attn  = (float*)(ws + 262144);      // 256 B
  float* bcomb = (float*)(ws + 262400);      // 8192 B
  u16*   xT2   = (u16*)  (ws + 270592);      // 17,842,176 B
  u16*   wcomb = (u16*)  (ws + 18112768);    // 4,718,592 B (end ~22.8 MB)

  xpose_pool<<<512, 256, 0, stream>>>(x, xT2, part);
  attn_fc<<<16, 128, 0, stream>>>(part, w1, w2, b2, attn);
  combine<<<1024, 256, 0, stream>>>(W, bias, attn, wcomb, bcomb);

  (void)hipFuncSetAttribute(reinterpret_cast<const void*>(conv_mfma),
                            hipFuncAttributeMaxDynamicSharedMemorySize, 66560);
  conv_mfma<<<512, 256, 66560, stream>>>(xT2, wcomb, bcomb, out);
}

// Round 10
// 50.064 us; speedup vs baseline: 2.6142x; 1.1260x over previous
//
#include <hip/hip_runtime.h>
#include <cstdint>
#include <cstddef>

typedef unsigned short u16;
typedef __attribute__((ext_vector_type(8))) short short8;
typedef __attribute__((ext_vector_type(4))) float f32x4;

__device__ __forceinline__ u16 f2bf(float f){
  union { float f; unsigned u; } c; c.f = f;
  unsigned u = c.u;
  u += 0x7fffu + ((u >> 16) & 1u);   // RNE
  return (u16)(u >> 16);
}
__device__ __forceinline__ unsigned pk2(float a, float b){
  union { float f; unsigned u; } ca, cb; ca.f = a; cb.f = b;
  return ((ca.u + 0x8000u) >> 16) | ((cb.u + 0x8000u) & 0xFFFF0000u);
}

// xT2 layout: [b][row 0..65][col 0..65][128ci] bf16, interior at (h+1, w+1).
#define XB_STRIDE 557568   // 66*66*128 (u16 elements)
#define XR_STRIDE 8448     // 66*128

// wcomb layout (u16): b*147456 + ((tap*4+cq)<<12) + (co<<5) + ciq
//   where ci = cq*32 + ciq. One (tap,cq) slab = 128co x 32ci = 8KB, linear.

// direct-to-LDS 16B async copy
#define GLD_LDS(gsrc, ldst) \
  __builtin_amdgcn_global_load_lds((const __attribute__((address_space(1))) void*)(gsrc), \
                                   (__attribute__((address_space(3))) void*)(ldst), 16, 0, 0)

// ---------------------------------------------------------------------------
// Kernel 1: transpose x [b][128ci][4096] fp32 -> padded xT2 bf16 + SE pool
// partials. chunk==0 blocks also zero xT2[b]'s halo ring.
// 1D grid 512, b = bid&15 (bid%8 == b%8 -> L2 homing).
// ---------------------------------------------------------------------------
__global__ __launch_bounds__(256) void xpose_pool(
    const float* __restrict__ x, u16* __restrict__ xT2, float* __restrict__ part)
{
  const int bid = blockIdx.x;
  const int b = bid & 15, chunk = bid >> 4;
  const int pos0 = chunk << 7;
  const int tid = threadIdx.x;
  __shared__ u16 tile[16384];        // 32 KB, swizzled [row][g'][8ci]
  __shared__ float psum[128 * 33];
  const float* xb = x + ((size_t)b << 19) + pos0;
  const int p4 = (tid & 31) << 2;
  const int swz = (tid & 31) & 7;

  if (chunk == 0){                   // fused halo zeroing (disjoint from interior)
    u16* xh = xT2 + (size_t)b * XB_STRIDE;
    for (int i = tid; i < 4160; i += 256){     // 260 pos * 16 granules
      const int p = i >> 4, oct = i & 15;
      int row, col;
      if (p < 66)      { row = 0;        col = p; }
      else if (p < 132){ row = 65;       col = p - 66; }
      else if (p < 196){ row = p - 131;  col = 0; }
      else             { row = p - 195;  col = 65; }
      *(uint4*)(xh + row * XR_STRIDE + (col << 7) + (oct << 3)) =
          make_uint4(0u, 0u, 0u, 0u);
    }
  }

  #pragma unroll
  for (int i = 0; i < 2; ++i){
    const int gci = (tid >> 5) + (i << 3);
    const int ci8 = gci << 3;
    float4 L[8];
    #pragma unroll
    for (int j = 0; j < 8; ++j)
      L[j] = *(const float4*)(xb + ((size_t)(ci8 + j) << 12) + p4);
    #pragma unroll
    for (int j = 0; j < 8; ++j)
      psum[(ci8 + j) * 33 + (tid & 31)] = L[j].x + L[j].y + L[j].z + L[j].w;
    const int gs = gci ^ swz;
    const float* e = (const float*)L;
    #pragma unroll
    for (int p = 0; p < 4; ++p){
      const int row = p4 + p;
      uint4 V;
      V.x = pk2(e[0 * 4 + p], e[1 * 4 + p]);
      V.y = pk2(e[2 * 4 + p], e[3 * 4 + p]);
      V.z = pk2(e[4 * 4 + p], e[5 * 4 + p]);
      V.w = pk2(e[6 * 4 + p], e[7 * 4 + p]);
      *(uint4*)(tile + (row << 7) + (gs << 3)) = V;
    }
  }
  __syncthreads();

  if (tid < 128){
    float s = 0.f;
    #pragma unroll 8
    for (int j = 0; j < 32; ++j) s += psum[tid * 33 + j];
    part[((b << 5) + chunk) * 128 + tid] = s;
  }

  u16* xo = xT2 + (size_t)b * XB_STRIDE;
  const int g = tid & 15, rb = (tid >> 4) << 3;
  #pragma unroll
  for (int r = 0; r < 8; ++r){
    const int row = rb + r;
    const int gs = g ^ ((row >> 2) & 7);
    uint4 v = *(const uint4*)(tile + (row << 7) + (gs << 3));
    const int pos = pos0 + row;
    const int h = pos >> 6, w = pos & 63;
    *(uint4*)(xo + (h + 1) * XR_STRIDE + ((w + 1) << 7) + (g << 3)) = v;
  }
}

// ---------------------------------------------------------------------------
// Kernel 2: finish pooling, SE MLP, softmax(logits/30) -> attn[16][4]
// ---------------------------------------------------------------------------
__global__ void attn_fc(const float* __restrict__ part, const float* __restrict__ w1,
                        const float* __restrict__ w2, const float* __restrict__ b2,
                        float* __restrict__ attn)
{
  const int b = blockIdx.x, t = threadIdx.x;
  __shared__ float sp[128];
  __shared__ float sh[33];
  __shared__ float sl[4];
  const float* pb = part + (b << 12);
  float s = 0.f;
  for (int c = 0; c < 32; ++c) s += pb[(c << 7) + t];
  sp[t] = s * (1.f / 4096.f);
  __syncthreads();
  if (t < 33){
    float h = 0.f;
    for (int ci = 0; ci < 128; ++ci) h += sp[ci] * w1[t * 128 + ci];
    sh[t] = fmaxf(h, 0.f);
  }
  __syncthreads();
  if (t < 4){
    float l = b2[t];
    for (int j = 0; j < 33; ++j) l += sh[j] * w2[t * 33 + j];
    sl[t] = l * (1.f / 30.f);
  }
  __syncthreads();
  if (t == 0){
    float m = fmaxf(fmaxf(sl[0], sl[1]), fmaxf(sl[2], sl[3]));
    float e0 = __expf(sl[0] - m), e1 = __expf(sl[1] - m);
    float e2 = __expf(sl[2] - m), e3 = __expf(sl[3] - m);
    float inv = 1.f / (e0 + e1 + e2 + e3);
    attn[(b << 2) + 0] = e0 * inv; attn[(b << 2) + 1] = e1 * inv;
    attn[(b << 2) + 2] = e2 * inv; attn[(b << 2) + 3] = e3 * inv;
  }
}

// ---------------------------------------------------------------------------
// Kernel 3: combine via LDS-staged W slice. grid 1024 = cp(64 co-pairs)
// *16 + b (bid%8==b%8 -> homing). Stage 2co x 4 branches x 1152 floats
// (36.9KB) via global_load_lds, then compute from LDS (stride-9 reads,
// 9 coprime 32 -> conflict-free). Writes linear quarter-major wcomb.
// ---------------------------------------------------------------------------
__global__ __launch_bounds__(256) void combine(
    const float* __restrict__ W, const float* __restrict__ bias,
    const float* __restrict__ attn, u16* __restrict__ wcomb,
    float* __restrict__ bcomb)
{
  __shared__ float wlds[9216];   // [k][co_l][1152]
  const int bid = blockIdx.x;
  const int b = bid & 15, cp = bid >> 4;    // cp: co-pair 0..63
  const int tid = threadIdx.x;
  const float a0 = attn[(b << 2) + 0], a1 = attn[(b << 2) + 1];
  const float a2 = attn[(b << 2) + 2], a3 = attn[(b << 2) + 3];

  // stage W[k][cp*2+co_l][:] : 2304 granules of 16B, linear per (k,co)
  #pragma unroll
  for (int it = 0; it < 9; ++it){
    const int G = it * 256 + tid;
    const int k = G / 576, rem = G - k * 576;
    const int co_l = rem / 288, j4 = rem - co_l * 288;
    const float* src = W + (size_t)(k * 128 + (cp << 1) + co_l) * 1152 + (j4 << 2);
    GLD_LDS(src, (char*)wlds + (G << 4));
  }

  if (tid < 2){
    const int co = (cp << 1) + tid;
    bcomb[(b << 7) + co] = a0 * bias[co] + a1 * bias[128 + co]
                         + a2 * bias[256 + co] + a3 * bias[384 + co];
  }
  asm volatile("s_waitcnt vmcnt(0)" ::: "memory");
  __syncthreads();

  u16* wob = wcomb + (size_t)b * 147456;
  for (int gi = tid; gi < 288; gi += 256){  // 2co * 9tap * (4cq*4g) granules
    const int co_l = gi / 144;
    const int r = gi - co_l * 144;
    const int tap = r >> 4;
    const int gg = r & 15;
    const int cq = gg >> 2, g = gg & 3;
    const int co = (cp << 1) + co_l;
    union { u16 h[8]; uint4 v; } pk;
    #pragma unroll
    for (int e = 0; e < 8; ++e){
      const int ci = (cq << 5) + (g << 3) + e;
      const int j = ci * 9 + tap;
      float s = a0 * wlds[co_l * 1152 + j]        + a1 * wlds[2304 + co_l * 1152 + j]
              + a2 * wlds[4608 + co_l * 1152 + j] + a3 * wlds[6912 + co_l * 1152 + j];
      pk.h[e] = f2bf(s);
    }
    *(uint4*)(wob + (((tap << 2) + cq) << 12) + (co << 5) + (g << 3)) = pk.v;
  }
}

// ---------------------------------------------------------------------------
// Kernel 4 (v9b): ci-quarter implicit GEMM. x-quarter (4row x 66col x 32ci =
// 16.9KB) staged once per 9 taps; 8KB weight slabs stream (dbuf, 2 loads/thr,
// T3 2-phase). 36 fine steps x 16 MFMA/wave. ALL LDS accesses contiguous
// 1024B wave reads (no swizzle). LDS 33.3KB. grid 512 x 256 thr (4 waves:
// wr=h-row, wcv=co-half), b homed to XCD b%8.
// FIX vs v9: STAGE_W granule offset is G<<3 u16 (16B), was G<<4 (32B stride
// -> half the slab left poisoned -> NaN).
// ---------------------------------------------------------------------------
__global__ __launch_bounds__(256, 2) void conv_mfma(
    const u16* __restrict__ xT2, const u16* __restrict__ wcomb,
    const float* __restrict__ bcomb, float* __restrict__ out)
{
  extern __shared__ char smem[];
  u16* s_x = (u16*)smem;               // [4row][66col][4oct][8ci] = 16896B
  u16* s_w = (u16*)(smem + 16896);     // 2 x 4096 u16 (8KB slabs)

  const int tid = threadIdx.x;
  const int lane = tid & 63, wid = tid >> 6;
  const int wr = wid & 1, wcv = wid >> 1;    // wr: h-row, wcv: co-half
  const int l15 = lane & 15, hi = lane >> 4;

  const int bid = blockIdx.x;
  const int b = bid & 15;                    // bid%8 == b%8 (L2 homing)
  const int h0 = (bid >> 4) << 1;            // 2 output rows

  const u16* Abase = wcomb + (size_t)b * 147456;
  const u16* Xbase = xT2 + (size_t)b * XB_STRIDE;

  // stage x quarter Q: 1056 granules; LDS [row][col][oct][8], linear source.
#define STAGE_X(Q) { \
    _Pragma("unroll") \
    for (int _it = 0; _it < 5; ++_it){ \
      const int _G = _it * 256 + tid; \
      if (_it < 4 || _G < 1056){ \
        const int _oct = _G & 3, _t = _G >> 2; \
        const int _col = _t % 66, _row = _t / 66; \
        const u16* _src = Xbase + (h0 + _row) * XR_STRIDE + (_col << 7) \
                        + ((Q) << 5) + (_oct << 3); \
        GLD_LDS(_src, s_x + (_G << 3)); \
      } \
    } }

#define STAGE_W(Q, TAP, BUF) { \
    const u16* _As = Abase + (((((TAP) << 2) + (Q))) << 12); \
    u16* _sw = s_w + (BUF) * 4096; \
    GLD_LDS(_As + (tid << 3), _sw + (tid << 3)); \
    GLD_LDS(_As + ((tid + 256) << 3), _sw + ((tid + 256) << 3)); }

#define COMPUTE(TAP, BUF) { \
    const int _dh = (TAP) / 3, _dw = (TAP) - 3 * (_dh); \
    const u16* _sw = s_w + (BUF) * 4096; \
    short8 _af[4], _bf[4]; \
    _Pragma("unroll") \
    for (int _a = 0; _a < 4; ++_a){ \
      const int _co = (wcv << 6) + (_a << 4) + l15; \
      _af[_a] = *(const short8*)(_sw + (_co << 5) + (hi << 3)); \
    } \
    _Pragma("unroll") \
    for (int _p = 0; _p < 4; ++_p){ \
      const int _col = l15 + _dw + (_p << 4); \
      _bf[_p] = *(const short8*)(s_x + (((wr + _dh) * 66 + _col) << 5) + (hi << 3)); \
    } \
    _Pragma("unroll") \
    for (int _a = 0; _a < 4; ++_a) \
      _Pragma("unroll") \
      for (int _p = 0; _p < 4; ++_p) \
        acc[_a][_p] = __builtin_amdgcn_mfma_f32_16x16x32_bf16(_af[_a], _bf[_p], acc[_a][_p], 0, 0, 0); }

#define VM0_BAR { asm volatile("s_waitcnt vmcnt(0)" ::: "memory"); __syncthreads(); }

  f32x4 acc[4][4] = {};

  STAGE_X(0);
  STAGE_W(0, 0, 0);
  VM0_BAR;

  int buf = 0;
  for (int q = 0; q < 4; ++q){
    #pragma unroll
    for (int tap = 0; tap < 9; ++tap){
      if (!(q == 3 && tap == 8)){
        const int nq = (tap == 8) ? q + 1 : q;
        const int nt = (tap == 8) ? 0 : tap + 1;
        STAGE_W(nq, nt, buf ^ 1);
      }
      COMPUTE(tap, buf);
      VM0_BAR;
      buf ^= 1;
      if (tap == 8 && q < 3){
        STAGE_X(q + 1);
        VM0_BAR;
      }
    }
  }

#undef VM0_BAR
#undef COMPUTE
#undef STAGE_W
#undef STAGE_X

  // ---- epilogue: C/D col=l15 (w), row=hi*4+r (co). NT stores. ----
  const int hrow = h0 + wr;
  float* ob = out + ((size_t)b << 19) + (hrow << 6) + l15;
  #pragma unroll
  for (int a = 0; a < 4; ++a){
    const int co0 = (wcv << 6) + (a << 4) + (hi << 2);
    #pragma unroll
    for (int r = 0; r < 4; ++r){
      const float bc = bcomb[(b << 7) + co0 + r];
      float* op = ob + (size_t)(co0 + r) * 4096;
      #pragma unroll
      for (int p = 0; p < 4; ++p)
        __builtin_nontemporal_store(acc[a][p][r] + bc, op + (p << 4));
    }
  }
}

// ---------------------------------------------------------------------------
extern "C" void kernel_launch(void* const* d_in, const int* in_sizes, int n_in,
                              void* d_out, int out_size, void* d_ws, size_t ws_size,
                              hipStream_t stream)
{
  const float* x    = (const float*)d_in[0];
  const float* W    = (const float*)d_in[1];
  const float* bias = (const float*)d_in[2];
  const float* w1   = (const float*)d_in[3];
  const float* w2   = (const float*)d_in[4];
  const float* b2   = (const float*)d_in[5];
  float* out = (float*)d_out;

  char* ws = (char*)d_ws;
  float* part  = (float*)(ws);               // 262144 B
  float* attn  = (float*)(ws + 262144);      // 256 B
  float* bcomb = (float*)(ws + 262400);      // 8192 B
  u16*   xT2   = (u16*)  (ws + 270592);      // 17,842,176 B
  u16*   wcomb = (u16*)  (ws + 18112768);    // 4,718,592 B (end ~22.8 MB)

  xpose_pool<<<512, 256, 0, stream>>>(x, xT2, part);
  attn_fc<<<16, 128, 0, stream>>>(part, w1, w2, b2, attn);
  combine<<<1024, 256, 0, stream>>>(W, bias, attn, wcomb, bcomb);

  (void)hipFuncSetAttribute(reinterpret_cast<const void*>(conv_mfma),
                            hipFuncAttributeMaxDynamicSharedMemorySize, 33280);
  conv_mfma<<<512, 256, 33280, stream>>>(xT2, wcomb, bcomb, out);
}